// Round 1
// baseline (2187.102 us; speedup 1.0000x reference)
//
#include <hip/hip_runtime.h>

constexpr int BN = 512;
constexpr int NITER = 50;

#define TAUF 1000.0f
#define CEXP (-28.853900817779268f)   /* -log2(e)/0.05 */

__device__ __forceinline__ float fexp2(float x) { return __builtin_amdgcn_exp2f(x); }
__device__ __forceinline__ float flog2(float x) { return __builtin_amdgcn_logf(x); }

__global__ __launch_bounds__(512)
void sinkhorn512(const float* __restrict__ X, float* __restrict__ out)
{
    const int b = blockIdx.x;
    const int t = threadIdx.x;        // 0..511
    const int lane = t & 63;
    const int wv = t >> 6;            // 0..7

    const float* __restrict__ M = X + (size_t)b * (BN * BN);
    float* __restrict__ G = out + (size_t)b * (BN * BN);

    __shared__ float s_ar[BN];   // alpha * log2e / reg
    __shared__ float s_br[BN];   // beta  * log2e / reg
    __shared__ float s_u[BN];
    __shared__ float s_v[BN];
    __shared__ float s_cu[BN];   // s_ar + log2(u)
    __shared__ float s_cv[BN];   // s_br + log2(v)
    __shared__ float s_wmax[16]; // [0..7] = per-wave max|u|, [8..15] = max|v|

    const float invN = 1.0f / (float)BN;
    s_ar[t] = 0.0f;
    s_br[t] = 0.0f;
    s_u[t]  = invN;
    s_v[t]  = invN;
    __syncthreads();

    for (int it = 0; it < NITER; ++it) {
        // cu_i = alpha2_i + log2(u_i)
        s_cu[t] = s_ar[t] + flog2(s_u[t]);
        __syncthreads();

        // ---- v = 1 / (K^T u) : thread t owns column j = t, loop over rows ----
        {
            const float bj = s_br[t];
            const float* p = M + t;
            float a0 = 0.f, a1 = 0.f, a2 = 0.f, a3 = 0.f;
            #pragma unroll 4
            for (int i = 0; i < BN; i += 4) {
                float m0 = p[(i + 0) * BN];
                float m1 = p[(i + 1) * BN];
                float m2 = p[(i + 2) * BN];
                float m3 = p[(i + 3) * BN];
                a0 += fexp2(fmaf(m0, CEXP, s_cu[i + 0] + bj));
                a1 += fexp2(fmaf(m1, CEXP, s_cu[i + 1] + bj));
                a2 += fexp2(fmaf(m2, CEXP, s_cu[i + 2] + bj));
                a3 += fexp2(fmaf(m3, CEXP, s_cu[i + 3] + bj));
            }
            const float s  = (a0 + a1) + (a2 + a3);
            const float vj = 1.0f / s;
            s_v[t]  = vj;
            s_cv[t] = bj + flog2(vj);
            float mv = fabsf(vj);
            #pragma unroll
            for (int m = 32; m >= 1; m >>= 1) mv = fmaxf(mv, __shfl_xor(mv, m, 64));
            if (lane == 0) s_wmax[8 + wv] = mv;
        }
        __syncthreads();

        // ---- u = 1 / (K v) : wave wv owns rows i = wv + 8*r, float4 lane loads ----
        {
            const float4 cva = *reinterpret_cast<const float4*>(&s_cv[4 * lane]);
            const float4 cvb = *reinterpret_cast<const float4*>(&s_cv[256 + 4 * lane]);
            float umax = 0.0f;
            for (int r = 0; r < 64; r += 2) {
                const int i0 = wv + 8 * r;
                const int i1 = i0 + 8;
                const float ai0 = s_ar[i0];
                const float ai1 = s_ar[i1];
                const float4 ma0 = *reinterpret_cast<const float4*>(M + i0 * BN + 4 * lane);
                const float4 mb0 = *reinterpret_cast<const float4*>(M + i0 * BN + 256 + 4 * lane);
                const float4 ma1 = *reinterpret_cast<const float4*>(M + i1 * BN + 4 * lane);
                const float4 mb1 = *reinterpret_cast<const float4*>(M + i1 * BN + 256 + 4 * lane);

                float s0 = ((fexp2(fmaf(ma0.x, CEXP, ai0 + cva.x))
                           + fexp2(fmaf(ma0.y, CEXP, ai0 + cva.y)))
                          + (fexp2(fmaf(ma0.z, CEXP, ai0 + cva.z))
                           + fexp2(fmaf(ma0.w, CEXP, ai0 + cva.w))))
                          + ((fexp2(fmaf(mb0.x, CEXP, ai0 + cvb.x))
                           + fexp2(fmaf(mb0.y, CEXP, ai0 + cvb.y)))
                          + (fexp2(fmaf(mb0.z, CEXP, ai0 + cvb.z))
                           + fexp2(fmaf(mb0.w, CEXP, ai0 + cvb.w))));

                float s1 = ((fexp2(fmaf(ma1.x, CEXP, ai1 + cva.x))
                           + fexp2(fmaf(ma1.y, CEXP, ai1 + cva.y)))
                          + (fexp2(fmaf(ma1.z, CEXP, ai1 + cva.z))
                           + fexp2(fmaf(ma1.w, CEXP, ai1 + cva.w))))
                          + ((fexp2(fmaf(mb1.x, CEXP, ai1 + cvb.x))
                           + fexp2(fmaf(mb1.y, CEXP, ai1 + cvb.y)))
                          + (fexp2(fmaf(mb1.z, CEXP, ai1 + cvb.z))
                           + fexp2(fmaf(mb1.w, CEXP, ai1 + cvb.w))));

                #pragma unroll
                for (int m = 32; m >= 1; m >>= 1) {
                    s0 += __shfl_xor(s0, m, 64);
                    s1 += __shfl_xor(s1, m, 64);
                }
                const float u0 = 1.0f / s0;
                const float u1 = 1.0f / s1;
                if (lane == 0) { s_u[i0] = u0; s_u[i1] = u1; }
                umax = fmaxf(umax, fmaxf(fabsf(u0), fabsf(u1)));
            }
            if (lane == 0) s_wmax[wv] = umax;
        }
        __syncthreads();

        // ---- absorption (block-uniform branch) ----
        float mu = s_wmax[0], mv = s_wmax[8];
        #pragma unroll
        for (int w = 1; w < 8; ++w) {
            mu = fmaxf(mu, s_wmax[w]);
            mv = fmaxf(mv, s_wmax[8 + w]);
        }
        if (mu > TAUF || mv > TAUF) {
            s_ar[t] += flog2(s_u[t]);
            s_br[t] += flog2(s_v[t]);
            s_u[t] = invN;
            s_v[t] = invN;
        }
        __syncthreads();
    }

    // ---- Gamma = exp2(cu_i + cv_j - M*log2e/reg) ----
    s_cu[t] = s_ar[t] + flog2(s_u[t]);
    s_cv[t] = s_br[t] + flog2(s_v[t]);
    __syncthreads();
    {
        const float cj = s_cv[t];
        const float* p = M + t;
        float* g = G + t;
        #pragma unroll 4
        for (int i = 0; i < BN; ++i) {
            g[i * BN] = fexp2(fmaf(p[i * BN], CEXP, s_cu[i] + cj));
        }
    }
}

extern "C" void kernel_launch(void* const* d_in, const int* in_sizes, int n_in,
                              void* d_out, int out_size, void* d_ws, size_t ws_size,
                              hipStream_t stream)
{
    const float* X = (const float*)d_in[0];
    float* out = (float*)d_out;
    const int batch = in_sizes[0] / (BN * BN);   // 128
    sinkhorn512<<<batch, 512, 0, stream>>>(X, out);
}

// Round 2
// 1287.815 us; speedup vs baseline: 1.6983x; 1.6983x over previous
//
#include <hip/hip_runtime.h>

constexpr int BN = 512;
constexpr int NITER = 50;

#define CEXP  (-28.853900817779268f)  /* -log2(e)/0.05 */
#define ESH   (14.0f)                 /* store E' = 2^(M*CEXP + 14) in fp16: range (2^-14.85, 2^14] */
#define L2TAU (9.965784284662087f)    /* log2(1000) */

typedef unsigned int u32;

__device__ __forceinline__ float fexp2(float x) { return __builtin_amdgcn_exp2f(x); }
__device__ __forceinline__ float flog2(float x) { return __builtin_amdgcn_logf(x); }

__device__ __forceinline__ float nr_rcp(float x) {
    float r = __builtin_amdgcn_rcpf(x);
    r = fmaf(r, fmaf(-x, r, 1.0f), r);   // one Newton step -> ~0.5 ulp
    return r;
}

template <int CTRL>
__device__ __forceinline__ float dpp_mov0(float x) {
    // old = 0, so invalid-source lanes contribute 0 regardless of bound_ctrl convention
    return __int_as_float(__builtin_amdgcn_update_dpp(
        0, __float_as_int(x), CTRL, 0xF, 0xF, true));
}

// full-wave (64-lane) sum; result valid on lane 63
__device__ __forceinline__ float wave_sum64(float x) {
    x += dpp_mov0<0x111>(x);  // row_shr:1
    x += dpp_mov0<0x112>(x);  // row_shr:2
    x += dpp_mov0<0x114>(x);  // row_shr:4
    x += dpp_mov0<0x118>(x);  // row_shr:8  -> lane15 of each row has row sum
    x += dpp_mov0<0x142>(x);  // row_bcast:15
    x += dpp_mov0<0x143>(x);  // row_bcast:31 -> lane 63 total
    return x;
}

// full-wave max; result valid on lane 63. 0-injection from invalid lanes only
// pulls negative maxima toward 0, which cannot flip a (> 9.97) comparison.
__device__ __forceinline__ float wave_max64(float x) {
    x = fmaxf(x, dpp_mov0<0x111>(x));
    x = fmaxf(x, dpp_mov0<0x112>(x));
    x = fmaxf(x, dpp_mov0<0x114>(x));
    x = fmaxf(x, dpp_mov0<0x118>(x));
    x = fmaxf(x, dpp_mov0<0x142>(x));
    x = fmaxf(x, dpp_mov0<0x143>(x));
    return x;
}

// accLo += f16lo(e2) * pLo ; accHi += f16hi(e2) * pHi   (single VALU op each)
__device__ __forceinline__ void fma_mix2(float& accLo, float& accHi, u32 e2,
                                         float pLo, float pHi) {
    asm("v_fma_mix_f32 %0, %2, %3, %0 op_sel_hi:[1,0,0]\n\t"
        "v_fma_mix_f32 %1, %2, %4, %1 op_sel:[1,0,0] op_sel_hi:[1,0,0]"
        : "+v"(accLo), "+v"(accHi)
        : "v"(e2), "v"(pLo), "v"(pHi));
}

// ---------------- Kernel A: E' = fp16(2^(M*CEXP+14)), stored transposed ----------------
// E'^T for matrix b occupies the first 512KB of output slot b (overwritten by Gamma later).
__global__ __launch_bounds__(256)
void prep_exp_t(const float* __restrict__ X, float* __restrict__ out)
{
    const int blk  = blockIdx.x;
    const int b    = blk >> 4;
    const int tile = blk & 15;
    const int i0   = (tile >> 2) << 7;
    const int j0   = (tile & 3) << 7;
    const int tid  = threadIdx.x;

    const float* __restrict__ Mb = X + (size_t)b * (BN * BN);
    _Float16* __restrict__ Et = reinterpret_cast<_Float16*>(out + (size_t)b * (BN * BN));

    __shared__ _Float16 T[128][130];   // +2 pad: kills the 64-way transpose-write conflict

    #pragma unroll
    for (int k = 0; k < 16; ++k) {
        int idx = tid + (k << 8);          // 0..4095 float4s
        int fi  = idx >> 5;                // tile row 0..127
        int fj  = idx & 31;                // float4 within row
        float4 m = *reinterpret_cast<const float4*>(Mb + (size_t)(i0 + fi) * BN + j0 + (fj << 2));
        T[(fj << 2) + 0][fi] = (_Float16)fexp2(fmaf(m.x, CEXP, ESH));
        T[(fj << 2) + 1][fi] = (_Float16)fexp2(fmaf(m.y, CEXP, ESH));
        T[(fj << 2) + 2][fi] = (_Float16)fexp2(fmaf(m.z, CEXP, ESH));
        T[(fj << 2) + 3][fi] = (_Float16)fexp2(fmaf(m.w, CEXP, ESH));
    }
    __syncthreads();
    #pragma unroll
    for (int k = 0; k < 32; ++k) {
        int o  = tid + (k << 8);           // 0..8191 half2s
        int j  = o >> 6;                   // 0..127
        int c2 = o & 63;
        u32 val = *reinterpret_cast<const u32*>(&T[j][c2 << 1]);
        *reinterpret_cast<u32*>(Et + (size_t)(j0 + j) * BN + i0 + (c2 << 1)) = val;
    }
}

// ---------------- Kernel B: 50 fused iterations + Gamma ----------------
__global__ __launch_bounds__(512)
void sinkhorn_iter(const float* __restrict__ X, float* __restrict__ out)
{
    const int b    = blockIdx.x;
    const int tid  = threadIdx.x;
    const int lane = tid & 63;
    const int w    = tid >> 6;

    const _Float16* __restrict__ Et =
        reinterpret_cast<const _Float16*>(out + (size_t)b * (BN * BN));
    const u32* __restrict__ Et4 = reinterpret_cast<const u32*>(Et);

    __shared__ float ah[BN], bh[BN], lu[BN], lv[BN], pv[BN];
    __shared__ float tpart[8][BN];
    __shared__ float wmaxlu[8], wmaxlv[8];

    ah[tid] = 0.0f; bh[tid] = 0.0f;
    lu[tid] = -9.0f; lv[tid] = -9.0f;
    pv[tid] = 0x1p-9f;                       // p = 2^(alpha+log2 u) = 2^-9
    __syncthreads();

    for (int it = 0; it < NITER; ++it) {
        float pr[8];
        *reinterpret_cast<float4*>(&pr[0]) = *reinterpret_cast<const float4*>(&pv[lane * 8]);
        *reinterpret_cast<float4*>(&pr[4]) = *reinterpret_cast<const float4*>(&pv[lane * 8 + 4]);

        float acc[8] = {0, 0, 0, 0, 0, 0, 0, 0};
        float vml = -1e30f;

        // wave w owns original-columns j in [64w, 64w+64): one contiguous 1KB E'^T row each
        #pragma unroll 4
        for (int cc = 0; cc < 64; ++cc) {
            const int j = (w << 6) + cc;
            const uint4 e = *reinterpret_cast<const uint4*>(Et4 + (size_t)j * 256 + lane * 4);

            float s0 = 0.0f, s1 = 0.0f;
            fma_mix2(s0, s1, e.x, pr[0], pr[1]);
            fma_mix2(s0, s1, e.y, pr[2], pr[3]);
            fma_mix2(s0, s1, e.z, pr[4], pr[5]);
            fma_mix2(s0, s1, e.w, pr[6], pr[7]);

            float sred = wave_sum64(s0 + s1);
            float sp = __int_as_float(__builtin_amdgcn_readlane(__float_as_int(sred), 63));
            float s  = sp * 0x1p-14f;        // undo E' scaling
            float q  = nr_rcp(s);            // q_j = 1/s_j
            float lvj = -bh[j] - flog2(s);   // log2 v_j
            vml = fmaxf(vml, lvj);
            if (lane == 0) lv[j] = lvj;

            fma_mix2(acc[0], acc[1], e.x, q, q);
            fma_mix2(acc[2], acc[3], e.y, q, q);
            fma_mix2(acc[4], acc[5], e.z, q, q);
            fma_mix2(acc[6], acc[7], e.w, q, q);
        }

        *reinterpret_cast<float4*>(&tpart[w][lane * 8]) =
            make_float4(acc[0], acc[1], acc[2], acc[3]);
        *reinterpret_cast<float4*>(&tpart[w][lane * 8 + 4]) =
            make_float4(acc[4], acc[5], acc[6], acc[7]);
        if (lane == 0) wmaxlv[w] = vml;
        __syncthreads();

        float t_s = 0.0f;
        #pragma unroll
        for (int w2 = 0; w2 < 8; ++w2) t_s += tpart[w2][tid];
        float t = t_s * 0x1p-14f;
        float lun = -ah[tid] - flog2(t);     // log2 u_i

        float redm = wave_max64(lun);
        if (lane == 63) wmaxlu[w] = redm;
        __syncthreads();

        float mlu = -1e30f, mlv = -1e30f;
        #pragma unroll
        for (int w2 = 0; w2 < 8; ++w2) {
            mlu = fmaxf(mlu, wmaxlu[w2]);
            mlv = fmaxf(mlv, wmaxlv[w2]);
        }
        const bool absorb = (mlu > L2TAU) || (mlv > L2TAU);

        if (absorb) {
            float an = ah[tid] + lun;        // alpha absorbs log u
            ah[tid] = an;
            lu[tid] = -9.0f;                 // u = 1/N
            pv[tid] = fexp2(an - 9.0f);      // p = 2^alpha / N
            bh[tid] += lv[tid];
            lv[tid] = -9.0f;
        } else {
            lu[tid] = lun;
            pv[tid] = nr_rcp(t);             // p = 1/t
        }
        __syncthreads();
    }

    // Gamma = 2^(M*CEXP + cu_i + cv_j), recomputed from fp32 M (overwrites E' in-slot)
    pv[tid] = ah[tid] + lu[tid];             // cu
    lv[tid] = bh[tid] + lv[tid];             // cv
    __syncthreads();

    const float cvj = lv[tid];
    const float* __restrict__ Mb = X + (size_t)b * (BN * BN);
    float* __restrict__ Gb = out + (size_t)b * (BN * BN);
    #pragma unroll 4
    for (int i = 0; i < BN; ++i) {
        Gb[(size_t)i * BN + tid] = fexp2(fmaf(Mb[(size_t)i * BN + tid], CEXP, pv[i] + cvj));
    }
}

extern "C" void kernel_launch(void* const* d_in, const int* in_sizes, int n_in,
                              void* d_out, int out_size, void* d_ws, size_t ws_size,
                              hipStream_t stream)
{
    const float* X = (const float*)d_in[0];
    float* out = (float*)d_out;
    const int batch = in_sizes[0] / (BN * BN);   // 128

    prep_exp_t<<<batch * 16, 256, 0, stream>>>(X, out);
    sinkhorn_iter<<<batch, 512, 0, stream>>>(X, out);
}

// Round 3
// 806.654 us; speedup vs baseline: 2.7113x; 1.5965x over previous
//
#include <hip/hip_runtime.h>

constexpr int BN = 512;
constexpr int NITER = 50;

#define CEXP  (-28.853900817779268f)  /* -log2(e)/0.05 */
#define ESH   (14.0f)                 /* E' = 2^(M*CEXP + 14) in fp16 */
#define L2TAU (9.965784284662087f)    /* log2(1000) */

typedef unsigned int u32;

__device__ __forceinline__ float fexp2(float x) { return __builtin_amdgcn_exp2f(x); }
__device__ __forceinline__ float flog2(float x) { return __builtin_amdgcn_logf(x); }

__device__ __forceinline__ float nr_rcp(float x) {
    float r = __builtin_amdgcn_rcpf(x);
    return fmaf(r, fmaf(-x, r, 1.0f), r);
}

template <int CTRL>
__device__ __forceinline__ float dppx(float x) {
    return __int_as_float(__builtin_amdgcn_update_dpp(
        0, __float_as_int(x), CTRL, 0xF, 0xF, true));
}

// all-lane-valid butterfly sum: xor1/2 (quad_perm), xor4 (half_mirror),
// xor8 (mirror), xor16/32 via shfl_xor. No readlane, no SALU hazard.
__device__ __forceinline__ float bfly_sum(float x) {
    x += dppx<0xB1>(x);
    x += dppx<0x4E>(x);
    x += dppx<0x141>(x);
    x += dppx<0x140>(x);
    x += __shfl_xor(x, 16, 64);
    x += __shfl_xor(x, 32, 64);
    return x;
}
__device__ __forceinline__ float bfly_max(float x) {
    x = fmaxf(x, dppx<0xB1>(x));
    x = fmaxf(x, dppx<0x4E>(x));
    x = fmaxf(x, dppx<0x141>(x));
    x = fmaxf(x, dppx<0x140>(x));
    x = fmaxf(x, __shfl_xor(x, 16, 64));
    x = fmaxf(x, __shfl_xor(x, 32, 64));
    return x;
}

// accLo += f16lo(e2)*pLo ; accHi += f16hi(e2)*pHi  (one VALU op each)
__device__ __forceinline__ void fma_mix2(float& accLo, float& accHi, u32 e2,
                                         float pLo, float pHi) {
    asm("v_fma_mix_f32 %0, %2, %3, %0 op_sel_hi:[1,0,0]\n\t"
        "v_fma_mix_f32 %1, %2, %4, %1 op_sel:[1,0,0] op_sel_hi:[1,0,0]"
        : "+v"(accLo), "+v"(accHi)
        : "v"(e2), "v"(pLo), "v"(pHi));
}

// ---------------- Kernel A: E' = fp16(2^(M*CEXP+14)), stored transposed ----------------
__global__ __launch_bounds__(256)
void prep_exp_t(const float* __restrict__ X, float* __restrict__ out)
{
    const int blk  = blockIdx.x;
    const int b    = blk >> 4;
    const int tile = blk & 15;
    const int i0   = (tile >> 2) << 7;
    const int j0   = (tile & 3) << 7;
    const int tid  = threadIdx.x;

    const float* __restrict__ Mb = X + (size_t)b * (BN * BN);
    _Float16* __restrict__ Et = reinterpret_cast<_Float16*>(out + (size_t)b * (BN * BN));

    __shared__ _Float16 T[128][130];

    #pragma unroll
    for (int k = 0; k < 16; ++k) {
        int idx = tid + (k << 8);
        int fi  = idx >> 5;
        int fj  = idx & 31;
        float4 m = *reinterpret_cast<const float4*>(Mb + (size_t)(i0 + fi) * BN + j0 + (fj << 2));
        T[(fj << 2) + 0][fi] = (_Float16)fexp2(fmaf(m.x, CEXP, ESH));
        T[(fj << 2) + 1][fi] = (_Float16)fexp2(fmaf(m.y, CEXP, ESH));
        T[(fj << 2) + 2][fi] = (_Float16)fexp2(fmaf(m.z, CEXP, ESH));
        T[(fj << 2) + 3][fi] = (_Float16)fexp2(fmaf(m.w, CEXP, ESH));
    }
    __syncthreads();
    #pragma unroll
    for (int k = 0; k < 32; ++k) {
        int o  = tid + (k << 8);
        int j  = o >> 6;
        int c2 = o & 63;
        u32 val = *reinterpret_cast<const u32*>(&T[j][c2 << 1]);
        *reinterpret_cast<u32*>(Et + (size_t)(j0 + j) * BN + i0 + (c2 << 1)) = val;
    }
}

// ---------------- Kernel B: 50 fused iterations + Gamma (1024 threads) ----------------
__global__ __launch_bounds__(1024, 4)
void sinkhorn_iter(const float* __restrict__ X, float* __restrict__ out)
{
    const int b    = blockIdx.x;
    const int t    = threadIdx.x;
    const int lane = t & 63;
    const int w    = t >> 6;            // 0..15

    const u32* __restrict__ Et4 =
        reinterpret_cast<const u32*>(out + (size_t)b * (BN * BN));

    __shared__ float ah[BN], bh[BN], lu[BN], lv[BN], pv[BN];
    __shared__ float tpart[16][BN];
    __shared__ float wmaxlu[8], wmaxlv[16];

    if (t < BN) {
        ah[t] = 0.f; bh[t] = 0.f;
        lu[t] = -9.f; lv[t] = -9.f;
        pv[t] = 0x1p-9f;
    }
    __syncthreads();

    for (int it = 0; it < NITER; ++it) {
        float pr[8];
        *reinterpret_cast<float4*>(&pr[0]) = *reinterpret_cast<const float4*>(&pv[lane * 8]);
        *reinterpret_cast<float4*>(&pr[4]) = *reinterpret_cast<const float4*>(&pv[lane * 8 + 4]);

        float acc[8] = {0, 0, 0, 0, 0, 0, 0, 0};
        float vml = -1e30f;
        const int jb0 = w << 5;          // 32 columns per wave

        uint4 e[4], f[4];
        #pragma unroll
        for (int c = 0; c < 4; ++c)
            e[c] = *reinterpret_cast<const uint4*>(Et4 + (size_t)(jb0 + c) * 256 + lane * 4);

        #pragma unroll
        for (int k = 0; k < 8; ++k) {
            const int jb = jb0 + 4 * k;
            if (k < 7) {
                #pragma unroll
                for (int c = 0; c < 4; ++c)
                    f[c] = *reinterpret_cast<const uint4*>(Et4 + (size_t)(jb + 4 + c) * 256 + lane * 4);
            }
            const float4 bh4 = *reinterpret_cast<const float4*>(&bh[jb]);
            float q[4], lvv[4];
            #pragma unroll
            for (int c = 0; c < 4; ++c) {
                float s0 = 0.f, s1 = 0.f;
                fma_mix2(s0, s1, e[c].x, pr[0], pr[1]);
                fma_mix2(s0, s1, e[c].y, pr[2], pr[3]);
                fma_mix2(s0, s1, e[c].z, pr[4], pr[5]);
                fma_mix2(s0, s1, e[c].w, pr[6], pr[7]);
                float s = bfly_sum(s0 + s1) * 0x1p-14f;
                q[c] = nr_rcp(s);
                const float bj = (c == 0) ? bh4.x : (c == 1) ? bh4.y : (c == 2) ? bh4.z : bh4.w;
                lvv[c] = -bj - flog2(s);
                vml = fmaxf(vml, lvv[c]);
            }
            if (lane == 0)
                *reinterpret_cast<float4*>(&lv[jb]) = make_float4(lvv[0], lvv[1], lvv[2], lvv[3]);
            #pragma unroll
            for (int c = 0; c < 4; ++c) {
                fma_mix2(acc[0], acc[1], e[c].x, q[c], q[c]);
                fma_mix2(acc[2], acc[3], e[c].y, q[c], q[c]);
                fma_mix2(acc[4], acc[5], e[c].z, q[c], q[c]);
                fma_mix2(acc[6], acc[7], e[c].w, q[c], q[c]);
            }
            #pragma unroll
            for (int c = 0; c < 4; ++c) e[c] = f[c];
        }

        *reinterpret_cast<float4*>(&tpart[w][lane * 8]) =
            make_float4(acc[0], acc[1], acc[2], acc[3]);
        *reinterpret_cast<float4*>(&tpart[w][lane * 8 + 4]) =
            make_float4(acc[4], acc[5], acc[6], acc[7]);
        if (lane == 0) wmaxlv[w] = vml;
        __syncthreads();

        float lun = 0.f, tt = 0.f;
        if (t < BN) {
            float p0 = 0, p1 = 0, p2 = 0, p3 = 0;
            #pragma unroll
            for (int w2 = 0; w2 < 16; w2 += 4) {
                p0 += tpart[w2 + 0][t];
                p1 += tpart[w2 + 1][t];
                p2 += tpart[w2 + 2][t];
                p3 += tpart[w2 + 3][t];
            }
            tt  = ((p0 + p1) + (p2 + p3)) * 0x1p-14f;
            lun = -ah[t] - flog2(tt);
            float m = bfly_max(lun);
            if (lane == 0) wmaxlu[w] = m;
        }
        __syncthreads();

        if (t < BN) {
            float mlu = wmaxlu[0], mlv = wmaxlv[0];
            #pragma unroll
            for (int i2 = 1; i2 < 8; ++i2)  mlu = fmaxf(mlu, wmaxlu[i2]);
            #pragma unroll
            for (int i2 = 1; i2 < 16; ++i2) mlv = fmaxf(mlv, wmaxlv[i2]);
            if (mlu > L2TAU || mlv > L2TAU) {
                float an = ah[t] + lun;
                ah[t] = an;
                lu[t] = -9.f;
                pv[t] = fexp2(an - 9.0f);
                bh[t] += lv[t];
                lv[t] = -9.f;
            } else {
                lu[t] = lun;
                pv[t] = nr_rcp(tt);
            }
        }
        __syncthreads();
    }

    if (t < BN) {
        pv[t] = ah[t] + lu[t];           // cu
        lv[t] = bh[t] + lv[t];           // cv
    }
    __syncthreads();

    const int j  = t & 511;
    const int i0 = (t >> 9) * 256;
    const float cvj = lv[j];
    const float* __restrict__ Mb = X + (size_t)b * (BN * BN);
    float* __restrict__ Gb = out + (size_t)b * (BN * BN);
    #pragma unroll 4
    for (int i = i0; i < i0 + 256; ++i)
        Gb[(size_t)i * BN + j] = fexp2(fmaf(Mb[(size_t)i * BN + j], CEXP, pv[i] + cvj));
}

extern "C" void kernel_launch(void* const* d_in, const int* in_sizes, int n_in,
                              void* d_out, int out_size, void* d_ws, size_t ws_size,
                              hipStream_t stream)
{
    const float* X = (const float*)d_in[0];
    float* out = (float*)d_out;
    const int batch = in_sizes[0] / (BN * BN);   // 128

    prep_exp_t<<<batch * 16, 256, 0, stream>>>(X, out);
    sinkhorn_iter<<<batch, 1024, 0, stream>>>(X, out);
}